// Round 6
// baseline (40.791 us; speedup 1.0000x reference)
//
#include <hip/hip_runtime.h>
#include <cmath>

#define NCLS 80
#define NB 16
#define NP 8400
#define NG 64
#define CHUNKS 33             // ceil(8400/256)
#define PBLK (NB * CHUNKS)    // 528 point-blocks
#define CB 1050               // cls-blocks: 1050 * 2560 float4 == N4 exactly
#define NBLK (CB + PBLK)      // 1578
#define N4 (NB * NP * NCLS / 4) // 2,688,000 float4s
#define EPSF 1e-7f

// Fast softplus-BCE via native v_exp/v_log (~2ulp; feeds a mean over 10.7M
// elems, threshold 9.2e-2 -> huge margin).
__device__ __forceinline__ float softplus_bce(float l) {
    float t = __expf(-fabsf(l));
    return fmaxf(l, 0.f) + __logf(1.f + t);
}

__device__ __forceinline__ float sp4(float4 c) {
    return (softplus_bce(c.x) + softplus_bce(c.y)) +
           (softplus_bce(c.z) + softplus_bce(c.w));
}

__device__ __forceinline__ float sanitize_box(float x) {
    if (isnan(x)) return 0.f;
    if (isinf(x)) x = (x > 0.f) ? 1000.f : 0.f;
    return fminf(fmaxf(x, -1000.f), 1000.f);
}

// Coherent (agent-scope, L1-bypassing) helpers: per-line write-through, NO L2
// flush — the cheap alternative to __threadfence() (R3: 1024 fences = +45us).
__device__ __forceinline__ void cstore(double* p, double v) {
    __hip_atomic_store(p, v, __ATOMIC_RELAXED, __HIP_MEMORY_SCOPE_AGENT);
}
__device__ __forceinline__ double cload(const double* p) {
    return __hip_atomic_load(p, __ATOMIC_RELAXED, __HIP_MEMORY_SCOPE_AGENT);
}

__global__ __launch_bounds__(256) void kFused(
    const float* __restrict__ pred_cls, const float* __restrict__ pred_obj,
    const float4* __restrict__ decoded, const float2* __restrict__ points,
    const float* __restrict__ strides, const float4* __restrict__ gt_boxes,
    const int* __restrict__ gt_labels,
    double* __restrict__ clsPart, double* __restrict__ pPart,
    unsigned* __restrict__ counter, float* __restrict__ out)
{
    const int bid = blockIdx.x, tid = threadIdx.x;

    if (bid < CB) {
        // ------------- cls softplus: one 2560-float4 tile, 2x5 loads -------------
        const float4* cls4 = (const float4*)pred_cls;
        const int base = bid * 2560 + tid;
        float4 a0 = cls4[base];
        float4 a1 = cls4[base + 256];
        float4 a2 = cls4[base + 512];
        float4 a3 = cls4[base + 768];
        float4 a4 = cls4[base + 1024];
        double acc = (double)sp4(a0) + (double)sp4(a1) + (double)sp4(a2) +
                     (double)sp4(a3) + (double)sp4(a4);
        float4 b0 = cls4[base + 1280];
        float4 b1 = cls4[base + 1536];
        float4 b2 = cls4[base + 1792];
        float4 b3 = cls4[base + 2048];
        float4 b4 = cls4[base + 2304];
        acc += (double)sp4(b0) + (double)sp4(b1) + (double)sp4(b2) +
               (double)sp4(b3) + (double)sp4(b4);

        __shared__ double shc[4];
        for (int off = 32; off; off >>= 1) acc += __shfl_down(acc, off, 64);
        if ((tid & 63) == 0) shc[tid >> 6] = acc;
        __syncthreads();
        if (tid == 0) cstore(&clsPart[bid], shc[0] + shc[1] + shc[2] + shc[3]);
    } else {
        // ------------- point path (verified exact R1-R5) -------------
        __shared__ float4 gbox[NG];
        __shared__ float garea[NG];
        __shared__ int glab[NG];

        const int pb = bid - CB;
        const int b = pb / CHUNKS;
        const int chunk = pb % CHUNKS;
        const int p = chunk * 256 + tid;

        if (tid < NG) {
            float4 gb = gt_boxes[b * NG + tid];
            gbox[tid] = gb;
            garea[tid] = (gb.z - gb.x) * (gb.w - gb.y);
            glab[tid] = gt_labels[b * NG + tid];
        }
        __syncthreads();

        double v1 = 0.0, v2 = 0.0, v3 = 0.0, v4 = 0.0;

        if (p < NP) {
            float2 pt = points[p];
            const float px = pt.x, py = pt.y;
            const float s = strides[p];
            const float r = s * 2.5f;
            const float fit_thr = s * 8.0f;

            unsigned long long match = 0ull, fallback = 0ull;
            #pragma unroll 4
            for (int g = 0; g < NG; ++g) {
                float4 gb = gbox[g];
                float d0 = px - gb.x, d1 = py - gb.y, d2 = gb.z - px, d3 = gb.w - py;
                float dmin = fminf(fminf(d0, d1), fminf(d2, d3));
                float dmax = fmaxf(fmaxf(d0, d1), fmaxf(d2, d3));
                bool ib = dmin > 0.f;
                float cx = (gb.x + gb.z) * 0.5f, cy = (gb.y + gb.w) * 0.5f;
                float c0 = px - (cx - r), c1 = py - (cy - r);
                float c2 = cx + r - px, c3 = cy + r - py;
                float cmin = fminf(fminf(c0, c1), fminf(c2, c3));
                bool fb = ib && (cmin > 0.f);
                bool m = fb && (dmax <= fit_thr);
                unsigned long long bit = 1ull << g;
                if (m) match |= bit;
                if (fb) fallback |= bit;
            }
            unsigned long long mask = match ? match : fallback;

            float lo = pred_obj[b * NP + p];
            float tobj = 0.f;

            if (mask) {
                int best = 0; float bestA = INFINITY;
                unsigned long long mm = mask;
                while (mm) {
                    int g = __ffsll((long long)mm) - 1;
                    mm &= mm - 1;
                    float a = garea[g];
                    if (a < bestA) { bestA = a; best = g; }
                }
                v1 = 1.0;

                float4 db = decoded[(size_t)b * NP + p];
                float x1 = sanitize_box(db.x);
                float y1 = sanitize_box(db.y);
                float x2 = fmaxf(x1 + 0.001f, sanitize_box(db.z));
                float y2 = fmaxf(y1 + 0.001f, sanitize_box(db.w));

                float4 g4 = gbox[best];
                float gx1 = g4.x, gy1 = g4.y, gx2 = g4.z, gy2 = g4.w;

                float w1 = x2 - x1, h1 = y2 - y1;
                float w2 = gx2 - gx1, h2 = gy2 - gy1;
                float iw = fmaxf(fminf(x2, gx2) - fmaxf(x1, gx1), 0.f);
                float ih = fmaxf(fminf(y2, gy2) - fmaxf(y1, gy1), 0.f);
                float inter = iw * ih;
                float uni = w1 * h1 + w2 * h2 - inter + EPSF;
                float iou = inter / uni;
                float cw = fmaxf(x2, gx2) - fminf(x1, gx1);
                float ch = fmaxf(y2, gy2) - fminf(y1, gy1);
                float c2d = cw * cw + ch * ch + EPSF;
                float dx = x1 + x2 - gx1 - gx2, dy = y1 + y2 - gy1 - gy2;
                float rho2 = (dx * dx + dy * dy) * 0.25f;
                float da = atanf(w2 / (h2 + EPSF)) - atanf(w1 / (h1 + EPSF));
                float vv = 0.40528473456935108577551785283891f * da * da; // 4/pi^2
                float alpha = vv / (1.f - iou + vv + EPSF);
                float ciou = 1.f - (iou - rho2 / c2d - alpha * vv);
                if (isnan(ciou) || isinf(ciou)) ciou = 1.f;
                ciou = fminf(fmaxf(ciou, 0.f), 2.f);
                v2 = (double)ciou;
                tobj = fminf(fmaxf(1.f - ciou, 0.f), 1.f);

                v4 = (double)pred_cls[((size_t)b * NP + p) * NCLS + glab[best]];
            }
            v3 = (double)(softplus_bce(lo) - lo * tobj);
        }

        __shared__ double sh[4][4];
        double vals[4] = {v1, v2, v3, v4};
        for (int k = 0; k < 4; ++k) {
            double v = vals[k];
            for (int off = 32; off; off >>= 1) v += __shfl_down(v, off, 64);
            if ((tid & 63) == 0) sh[k][tid >> 6] = v;
        }
        __syncthreads();
        if (tid == 0) {
            #pragma unroll
            for (int k = 0; k < 4; ++k)
                cstore(&pPart[(size_t)k * PBLK + pb],
                       sh[k][0] + sh[k][1] + sh[k][2] + sh[k][3]);
        }
    }

    // ---------------- signal; last arriver finalizes (no fence, no spin) --------
    __shared__ int lastFlag;
    if (tid == 0) {
        // drain our coherent partial stores to the coherent point BEFORE the RMW
        asm volatile("s_waitcnt vmcnt(0)" ::: "memory");
        unsigned old = __hip_atomic_fetch_add(counter, 1u, __ATOMIC_RELAXED,
                                              __HIP_MEMORY_SCOPE_AGENT);
        lastFlag = (old == (unsigned)(NBLK - 1)) ? 1 : 0;
    }
    __syncthreads();
    if (!lastFlag) return;

    // Every other block's partial stores were vmcnt-acked before its RMW, and
    // our RMW observed all of them -> coherent loads below see final values.
    double a[5] = {0, 0, 0, 0, 0};
    for (int i = tid; i < CB; i += 256) a[0] += cload(&clsPart[i]);
    #pragma unroll
    for (int k = 0; k < 4; ++k)
        for (int i = tid; i < PBLK; i += 256)
            a[1 + k] += cload(&pPart[(size_t)k * PBLK + i]);

    __shared__ double sh2[4];
    __shared__ double tot[5];
    for (int k = 0; k < 5; ++k) {
        double v = a[k];
        for (int off = 32; off; off >>= 1) v += __shfl_down(v, off, 64);
        __syncthreads();
        if ((tid & 63) == 0) sh2[tid >> 6] = v;
        __syncthreads();
        if (tid == 0) tot[k] = sh2[0] + sh2[1] + sh2[2] + sh2[3];
    }
    __syncthreads();
    if (tid == 0) {
        double cls_sum = tot[0], fg_sum = tot[1], box_sum = tot[2],
               obj_sum = tot[3], corr_sum = tot[4];

        float loss_cls = (float)((cls_sum - corr_sum) /
                                 (double)((size_t)NB * NP * NCLS));
        if (isnan(loss_cls)) loss_cls = 0.f;
        loss_cls = fminf(loss_cls, 10.f);

        float numfg = (float)fg_sum;
        float norm = fmaxf(numfg, 1.f);
        float loss_box = (float)box_sum / norm;
        if (isnan(loss_box)) loss_box = 0.f;
        loss_box = fminf(loss_box, 10.f);

        float loss_obj = (float)(obj_sum / (double)(NB * NP));
        if (isnan(loss_obj)) loss_obj = 0.f;
        loss_obj = fminf(loss_obj, 10.f);

        // CLS_W=0.5, BOX_W*WARMUP = 7.5/3 = 2.5, OBJ_W=1
        float total = 0.5f * loss_cls + 2.5f * loss_box + loss_obj;
        if (isnan(total)) total = 0.f;
        total = fminf(total, 10.f);

        out[0] = total; out[1] = loss_cls; out[2] = loss_box; out[3] = loss_obj;
    }
}

extern "C" void kernel_launch(void* const* d_in, const int* in_sizes, int n_in,
                              void* d_out, int out_size, void* d_ws, size_t ws_size,
                              hipStream_t stream) {
    const float*  pred_cls  = (const float*)d_in[0];
    // d_in[1] = pred_box: dead in the reference, never read
    const float*  pred_obj  = (const float*)d_in[2];
    const float4* decoded   = (const float4*)d_in[3];
    const float2* points    = (const float2*)d_in[4];
    const float*  strides   = (const float*)d_in[5];
    const float4* gt_boxes  = (const float4*)d_in[6];
    const int*    gt_labels = (const int*)d_in[7];

    double*   clsPart = (double*)d_ws;               // CB doubles
    double*   pPart   = clsPart + CB;                // 4*PBLK doubles
    unsigned* counter = (unsigned*)(pPart + 4 * PBLK);

    hipMemsetAsync(counter, 0, sizeof(unsigned), stream);  // graph-capturable

    kFused<<<NBLK, 256, 0, stream>>>(
        pred_cls, pred_obj, decoded, points, strides, gt_boxes, gt_labels,
        clsPart, pPart, counter, (float*)d_out);
}

// Round 7
// 24.282 us; speedup vs baseline: 1.6798x; 1.6798x over previous
//
#include <hip/hip_runtime.h>
#include <cmath>

#define NCLS 80
#define NB 16
#define NP 8400
#define NG 64
#define CHUNKS 33             // ceil(8400/256)
#define PBLK (NB * CHUNKS)    // 528 point-blocks
#define CB 1050               // cls-blocks: 1050 * 2560 float4 == N4 exactly
#define N4 (NB * NP * NCLS / 4) // 2,688,000 float4s
#define EPSF 1e-7f

// Fast softplus-BCE via native v_exp/v_log (~2ulp; feeds a mean over 10.7M
// elems, threshold 9.2e-2 -> huge margin).
__device__ __forceinline__ float softplus_bce(float l) {
    float t = __expf(-fabsf(l));
    return fmaxf(l, 0.f) + __logf(1.f + t);
}

__device__ __forceinline__ float sp4(float4 c) {
    return (softplus_bce(c.x) + softplus_bce(c.y)) +
           (softplus_bce(c.z) + softplus_bce(c.w));
}

__device__ __forceinline__ float sanitize_box(float x) {
    if (isnan(x)) return 0.f;
    if (isinf(x)) x = (x > 0.f) ? 1000.f : 0.f;
    return fminf(fmaxf(x, -1000.f), 1000.f);
}

// K1: blocks [0,PBLK) = point/assignment/CIoU/obj path (byte-identical math,
// verified exact R1-R6). blocks [PBLK, PBLK+CB) = cls softplus, one
// 2560-float4 tile per block, 2x5 independent loads per thread.
// No cross-block sync of any kind (R3/R6: in-kernel handoff costs 12-28us).
__global__ __launch_bounds__(256) void k1_main(
    const float* __restrict__ pred_cls, const float* __restrict__ pred_obj,
    const float4* __restrict__ decoded, const float2* __restrict__ points,
    const float* __restrict__ strides, const float4* __restrict__ gt_boxes,
    const int* __restrict__ gt_labels,
    double* __restrict__ clsPart, double* __restrict__ pPart)
{
    const int bid = blockIdx.x, tid = threadIdx.x;

    if (bid >= PBLK) {
        // ---------------- cls softplus: one 2560-float4 tile ----------------
        const float4* cls4 = (const float4*)pred_cls;
        const int base = (bid - PBLK) * 2560 + tid;
        float4 a0 = cls4[base];
        float4 a1 = cls4[base + 256];
        float4 a2 = cls4[base + 512];
        float4 a3 = cls4[base + 768];
        float4 a4 = cls4[base + 1024];
        double acc = (double)sp4(a0) + (double)sp4(a1) + (double)sp4(a2) +
                     (double)sp4(a3) + (double)sp4(a4);
        float4 b0 = cls4[base + 1280];
        float4 b1 = cls4[base + 1536];
        float4 b2 = cls4[base + 1792];
        float4 b3 = cls4[base + 2048];
        float4 b4 = cls4[base + 2304];
        acc += (double)sp4(b0) + (double)sp4(b1) + (double)sp4(b2) +
               (double)sp4(b3) + (double)sp4(b4);

        __shared__ double shc[4];
        for (int off = 32; off; off >>= 1) acc += __shfl_down(acc, off, 64);
        if ((tid & 63) == 0) shc[tid >> 6] = acc;
        __syncthreads();
        if (tid == 0) clsPart[bid - PBLK] = shc[0] + shc[1] + shc[2] + shc[3];
        return;
    }

    // ---------------- point path ----------------
    __shared__ float4 gbox[NG];
    __shared__ float garea[NG];
    __shared__ int glab[NG];

    const int b = bid / CHUNKS;
    const int chunk = bid % CHUNKS;
    const int p = chunk * 256 + tid;

    if (tid < NG) {
        float4 gb = gt_boxes[b * NG + tid];
        gbox[tid] = gb;
        garea[tid] = (gb.z - gb.x) * (gb.w - gb.y);
        glab[tid] = gt_labels[b * NG + tid];
    }
    __syncthreads();

    // v1=num_fg, v2=box_sum, v3=obj_sum, v4=corr_sum
    double v1 = 0.0, v2 = 0.0, v3 = 0.0, v4 = 0.0;

    if (p < NP) {
        float2 pt = points[p];
        const float px = pt.x, py = pt.y;
        const float s = strides[p];
        const float r = s * 2.5f;
        const float fit_thr = s * 8.0f;

        unsigned long long match = 0ull, fallback = 0ull;
        #pragma unroll 4
        for (int g = 0; g < NG; ++g) {
            float4 gb = gbox[g];
            float d0 = px - gb.x, d1 = py - gb.y, d2 = gb.z - px, d3 = gb.w - py;
            float dmin = fminf(fminf(d0, d1), fminf(d2, d3));
            float dmax = fmaxf(fmaxf(d0, d1), fmaxf(d2, d3));
            bool ib = dmin > 0.f;
            float cx = (gb.x + gb.z) * 0.5f, cy = (gb.y + gb.w) * 0.5f;
            float c0 = px - (cx - r), c1 = py - (cy - r);
            float c2 = cx + r - px, c3 = cy + r - py;
            float cmin = fminf(fminf(c0, c1), fminf(c2, c3));
            bool fb = ib && (cmin > 0.f);
            bool m = fb && (dmax <= fit_thr);
            unsigned long long bit = 1ull << g;
            if (m) match |= bit;
            if (fb) fallback |= bit;
        }
        unsigned long long mask = match ? match : fallback;

        float lo = pred_obj[b * NP + p];
        float tobj = 0.f;

        if (mask) {
            int best = 0; float bestA = INFINITY;
            unsigned long long mm = mask;
            while (mm) {
                int g = __ffsll((long long)mm) - 1;
                mm &= mm - 1;
                float a = garea[g];
                if (a < bestA) { bestA = a; best = g; }
            }
            v1 = 1.0;

            float4 db = decoded[(size_t)b * NP + p];
            float x1 = sanitize_box(db.x);
            float y1 = sanitize_box(db.y);
            float x2 = fmaxf(x1 + 0.001f, sanitize_box(db.z));
            float y2 = fmaxf(y1 + 0.001f, sanitize_box(db.w));

            float4 g4 = gbox[best];
            float gx1 = g4.x, gy1 = g4.y, gx2 = g4.z, gy2 = g4.w;

            float w1 = x2 - x1, h1 = y2 - y1;
            float w2 = gx2 - gx1, h2 = gy2 - gy1;
            float iw = fmaxf(fminf(x2, gx2) - fmaxf(x1, gx1), 0.f);
            float ih = fmaxf(fminf(y2, gy2) - fmaxf(y1, gy1), 0.f);
            float inter = iw * ih;
            float uni = w1 * h1 + w2 * h2 - inter + EPSF;
            float iou = inter / uni;
            float cw = fmaxf(x2, gx2) - fminf(x1, gx1);
            float ch = fmaxf(y2, gy2) - fminf(y1, gy1);
            float c2d = cw * cw + ch * ch + EPSF;
            float dx = x1 + x2 - gx1 - gx2, dy = y1 + y2 - gy1 - gy2;
            float rho2 = (dx * dx + dy * dy) * 0.25f;
            float da = atanf(w2 / (h2 + EPSF)) - atanf(w1 / (h1 + EPSF));
            float vv = 0.40528473456935108577551785283891f * da * da; // 4/pi^2
            float alpha = vv / (1.f - iou + vv + EPSF);
            float ciou = 1.f - (iou - rho2 / c2d - alpha * vv);
            if (isnan(ciou) || isinf(ciou)) ciou = 1.f;
            ciou = fminf(fmaxf(ciou, 0.f), 2.f);
            v2 = (double)ciou;
            tobj = fminf(fmaxf(1.f - ciou, 0.f), 1.f);

            v4 = (double)pred_cls[((size_t)b * NP + p) * NCLS + glab[best]];
        }
        v3 = (double)(softplus_bce(lo) - lo * tobj);
    }

    __shared__ double sh[4][4];
    double vals[4] = {v1, v2, v3, v4};
    for (int k = 0; k < 4; ++k) {
        double v = vals[k];
        for (int off = 32; off; off >>= 1) v += __shfl_down(v, off, 64);
        if ((tid & 63) == 0) sh[k][tid >> 6] = v;
    }
    __syncthreads();
    if (tid == 0) {
        #pragma unroll
        for (int k = 0; k < 4; ++k)
            pPart[(size_t)k * PBLK + bid] = sh[k][0] + sh[k][1] + sh[k][2] + sh[k][3];
    }
}

// K2: single-block (512 thr) deterministic reduce + combine. Latency-bound:
// <=3 strided load rounds per thread, one sync, scalar 8-wave combine.
__global__ __launch_bounds__(512) void k2_finalize(
    const double* __restrict__ clsPart, const double* __restrict__ pPart,
    float* __restrict__ out)
{
    const int tid = threadIdx.x;
    double a[5] = {0, 0, 0, 0, 0};
    // clsPart: 1050 entries, 512 threads -> 3 rounds (2 guarded)
    {
        double t0 = clsPart[tid];
        double t1 = (tid + 512 < CB) ? clsPart[tid + 512] : 0.0;
        double t2 = (tid + 1024 < CB) ? clsPart[tid + 1024] : 0.0;
        a[0] = (t0 + t1) + t2;
    }
    // pPart: 4 x 528, 512 threads -> 2 rounds (1 guarded)
    #pragma unroll
    for (int k = 0; k < 4; ++k) {
        double t0 = (tid < PBLK) ? pPart[(size_t)k * PBLK + tid] : 0.0;
        double t1 = (tid + 512 < PBLK) ? pPart[(size_t)k * PBLK + tid + 512] : 0.0;
        a[1 + k] = t0 + t1;
    }

    __shared__ double sh[8][5];
    #pragma unroll
    for (int k = 0; k < 5; ++k)
        for (int off = 32; off; off >>= 1) a[k] += __shfl_down(a[k], off, 64);
    if ((tid & 63) == 0) {
        #pragma unroll
        for (int k = 0; k < 5; ++k) sh[tid >> 6][k] = a[k];
    }
    __syncthreads();

    if (tid == 0) {
        double tot[5];
        #pragma unroll
        for (int k = 0; k < 5; ++k) {
            double v = 0.0;
            #pragma unroll
            for (int w = 0; w < 8; ++w) v += sh[w][k];
            tot[k] = v;
        }
        double cls_sum = tot[0], fg_sum = tot[1], box_sum = tot[2],
               obj_sum = tot[3], corr_sum = tot[4];

        float loss_cls = (float)((cls_sum - corr_sum) /
                                 (double)((size_t)NB * NP * NCLS));
        if (isnan(loss_cls)) loss_cls = 0.f;
        loss_cls = fminf(loss_cls, 10.f);

        float numfg = (float)fg_sum;
        float norm = fmaxf(numfg, 1.f);
        float loss_box = (float)box_sum / norm;
        if (isnan(loss_box)) loss_box = 0.f;
        loss_box = fminf(loss_box, 10.f);

        float loss_obj = (float)(obj_sum / (double)(NB * NP));
        if (isnan(loss_obj)) loss_obj = 0.f;
        loss_obj = fminf(loss_obj, 10.f);

        // CLS_W=0.5, BOX_W*WARMUP = 7.5/3 = 2.5, OBJ_W=1
        float total = 0.5f * loss_cls + 2.5f * loss_box + loss_obj;
        if (isnan(total)) total = 0.f;
        total = fminf(total, 10.f);

        out[0] = total; out[1] = loss_cls; out[2] = loss_box; out[3] = loss_obj;
    }
}

extern "C" void kernel_launch(void* const* d_in, const int* in_sizes, int n_in,
                              void* d_out, int out_size, void* d_ws, size_t ws_size,
                              hipStream_t stream) {
    const float*  pred_cls  = (const float*)d_in[0];
    // d_in[1] = pred_box: dead in the reference, never read
    const float*  pred_obj  = (const float*)d_in[2];
    const float4* decoded   = (const float4*)d_in[3];
    const float2* points    = (const float2*)d_in[4];
    const float*  strides   = (const float*)d_in[5];
    const float4* gt_boxes  = (const float4*)d_in[6];
    const int*    gt_labels = (const int*)d_in[7];

    double* clsPart = (double*)d_ws;          // CB doubles
    double* pPart   = clsPart + CB;           // 4*PBLK doubles

    k1_main<<<PBLK + CB, 256, 0, stream>>>(
        pred_cls, pred_obj, decoded, points, strides, gt_boxes, gt_labels,
        clsPart, pPart);
    k2_finalize<<<1, 512, 0, stream>>>(clsPart, pPart, (float*)d_out);
}